// Round 11
// baseline (202.231 us; speedup 1.0000x reference)
//
#include <hip/hip_runtime.h>
#include <math.h>

#define NCLS 10
#define CHUNK 2048
#define PDIM 64
#define LDE 68    // padded leading dim for 64x64 LDS matrices in logdet

typedef short bf16x8 __attribute__((ext_vector_type(8)));
typedef short s16x8 __attribute__((ext_vector_type(8)));
typedef float f32x4 __attribute__((ext_vector_type(4)));

__device__ __forceinline__ unsigned short bf16rn(float x) {
    unsigned u = __float_as_uint(x);
    return (unsigned short)((u + 0x7FFFu + ((u >> 16) & 1u)) >> 16);
}
__device__ __forceinline__ float bf16f(unsigned short h) {
    return __uint_as_float(((unsigned)h) << 16);
}

// tile index for (fi,fj), fi<=fj, in 0..9 (compile-time under full unroll)
#define TIDX(fi, fj) ((fi) * 4 + (fj) - ((fi) * ((fi) + 1)) / 2)

// ---------------------------------------------------------------------------
// ws layout (memset zeroes [0, 163844)):
//   0        float gram[10][4096]     163840   (upper triangle valid)
//   163840   unsigned ctr             4
//   163848   double contrib[11]       88
//   163936   int counts[10]           40
// ---------------------------------------------------------------------------

// Kernel 1: per-(chunk, class) Gram via MFMA (bf16 hi/lo split), with
// REGISTER-DIRECT fragment gather: no LDS staging, no barriers in the main
// loop. Lane l of a wave needs feature fi*16+(l&15) of rows 8*(l>>4)+e --
// a scalar global load per (fi,e) that is 16-lane contiguous (64B segments).
// Each wave independently does 32-row steps s = w, w+4, ...; per step:
// 1 ds_read_b128 of 8 row indices, 32 masked global loads, in-register
// hi/lo bf16 convert, 30 MFMAs (10 upper 16x16 tiles x {hh,hl,lh}).
// Cross-wave reduce via LDS atomics (no barrier needed), single upper-tri
// global flush per block.
__global__ __launch_bounds__(256, 3) void mcr_gram(
    const float* __restrict__ embed,
    const int* __restrict__ targets,
    float* __restrict__ gram,
    int* __restrict__ counts,
    int m)
{
    __shared__ alignas(16) unsigned short s_list[CHUNK];   // 4 KB
    __shared__ int s_cnt;
    __shared__ float s_gram[PDIM * PDIM];                  // 16 KB

    const int tid = threadIdx.x;
    const int cls = blockIdx.y;
    const int base = blockIdx.x * CHUNK;
    const int lane = tid & 63;
    const int w = tid >> 6;

    if (tid == 0) s_cnt = 0;
#pragma unroll
    for (int i = 0; i < 4; ++i)
        *reinterpret_cast<float4*>(&s_gram[(tid + 256 * i) * 4]) =
            make_float4(0.f, 0.f, 0.f, 0.f);
    __syncthreads();

    // ---- ballot-compacted gather of class row indices ----
    const int lim = (m - base < CHUNK) ? (m - base) : CHUNK;
    for (int i = tid; i < lim; i += 256) {
        const bool match = (targets[base + i] == cls);
        const unsigned long long mk = __ballot(match);
        const int cnt = __popcll(mk);
        int wbase = 0;
        if (lane == 0 && cnt) wbase = atomicAdd(&s_cnt, cnt);
        wbase = __shfl(wbase, 0);
        if (match) {
            const int pre = __popcll(mk & ((1ull << lane) - 1ull));
            s_list[wbase + pre] = (unsigned short)i;
        }
    }
    __syncthreads();
    const int n = s_cnt;
    if (n == 0) return;
    if (tid == 0) atomicAdd(&counts[cls], n);

    // ---- wave-independent, barrier-free MFMA main loop ----
    const int t16 = lane & 15;
    const int s4 = lane >> 4;

    f32x4 acc[10];
#pragma unroll
    for (int i = 0; i < 10; ++i) acc[i] = (f32x4){0.f, 0.f, 0.f, 0.f};

    const int nsteps = (n + 31) >> 5;
    for (int s = w; s < nsteps; s += 4) {
        const int rb = s * 32 + 8 * s4;          // 16B-aligned in s_list
        const s16x8 iv = *(const s16x8*)&s_list[rb];

        float x[4][8];
#pragma unroll
        for (int e = 0; e < 8; ++e) {
            const int r = rb + e;
            const bool v = (r < n);
            const int row = base + (int)(unsigned short)iv[e];
            const float* rp = embed + (size_t)row * PDIM + t16;
#pragma unroll
            for (int fi = 0; fi < 4; ++fi)
                x[fi][e] = v ? rp[fi * 16] : 0.0f;
        }

        bf16x8 fh[4], fl[4];
#pragma unroll
        for (int fi = 0; fi < 4; ++fi)
#pragma unroll
            for (int e = 0; e < 8; ++e) {
                const unsigned short h = bf16rn(x[fi][e]);
                fh[fi][e] = (short)h;
                fl[fi][e] = (short)bf16rn(x[fi][e] - bf16f(h));
            }

#pragma unroll
        for (int fi = 0; fi < 4; ++fi)
#pragma unroll
            for (int fj = fi; fj < 4; ++fj) {
                const int t = TIDX(fi, fj);
                acc[t] = __builtin_amdgcn_mfma_f32_16x16x32_bf16(fh[fi], fh[fj], acc[t], 0, 0, 0);
                acc[t] = __builtin_amdgcn_mfma_f32_16x16x32_bf16(fh[fi], fl[fj], acc[t], 0, 0, 0);
                acc[t] = __builtin_amdgcn_mfma_f32_16x16x32_bf16(fl[fi], fh[fj], acc[t], 0, 0, 0);
            }
    }

    // ---- cross-wave reduce via LDS atomics (safe without a barrier) ----
#pragma unroll
    for (int fi = 0; fi < 4; ++fi)
#pragma unroll
        for (int fj = fi; fj < 4; ++fj) {
            const int t = TIDX(fi, fj);
            const int a0 = fi * 16 + s4 * 4;
            const int bc = fj * 16 + t16;
#pragma unroll
            for (int j = 0; j < 4; ++j)
                atomicAdd(&s_gram[(a0 + j) * PDIM + bc], acc[t][j]);
        }
    __syncthreads();

    // ---- global flush (upper triangle, class slot) ----
    float* gk = gram + cls * (PDIM * PDIM);
#pragma unroll
    for (int k = 0; k < 16; ++k) {
        const int e = tid + 256 * k;
        const int a = e >> 6, bc = e & 63;
        if (a <= bc) atomicAdd(&gk[e], s_gram[e]);
    }
}

__device__ __forceinline__ float gU(const float* __restrict__ gram, int k, int a, int b) {
    const int lo = a < b ? a : b;
    const int hi = a < b ? b : a;
    return gram[k * (PDIM * PDIM) + lo * PDIM + hi];
}
__device__ __forceinline__ float gT(const float* __restrict__ gram, int k, int a, int b) {
    if (k < NCLS) return gU(gram, k, a, b);
    float s = 0.0f;
#pragma unroll
    for (int c = 0; c < NCLS; ++c) s += gU(gram, c, a, b);
    return s;
}

// Kernel 2 (fused): one block per matrix (k=0..9 class Grams, k=10 total).
// M = I + c*G, s = tr(M)/64, E = M/s - I (tr E == 0, spectral radius ~0.1).
// logdet(M) = 64*log(s) - tr(E^2)/2 + ... - tr(E^8)/8. Last block sums.
__global__ __launch_bounds__(256) void mcr_logdet(
    const float* __restrict__ gram,
    const int* __restrict__ counts,
    double* __restrict__ contrib,
    unsigned* __restrict__ ctr,
    float* __restrict__ out,
    int m)
{
    __shared__ float E[PDIM * LDE];
    __shared__ float F[PDIM * LDE];
    __shared__ float H[PDIM * LDE];
    __shared__ float G3[PDIM * LDE];
    __shared__ double s_red[4][7];
    __shared__ double s_alpha, s_beta, s_logs, s_w;

    const int tid = threadIdx.x;
    const int k = blockIdx.x;
    const bool tot = (k == NCLS);

    if (tid < PDIM) {
        double d = (double)gT(gram, k, tid, tid);
#pragma unroll
        for (int off = 32; off > 0; off >>= 1) d += __shfl_down(d, off);
        if (tid == 0) {
            const double trG = d;
            const double denom = tot ? (double)m : ((double)counts[k] + 1e-8);
            const double c = (double)PDIM / (denom * 0.01);
            const double s = 1.0 + c * trG / (double)PDIM;
            s_alpha = c / s;
            s_beta = 1.0 / s - 1.0;
            s_logs = (double)PDIM * log(s);
            s_w = tot ? -0.5 : 0.5 * denom / (double)m;
        }
    }
    __syncthreads();

    const double alpha = s_alpha;
    const double beta = s_beta;
    const int ta = (tid >> 4) << 2;
    const int tb = (tid & 15) << 2;

#pragma unroll
    for (int i = 0; i < 4; ++i) {
        const int a = ta + i;
#pragma unroll
        for (int j = 0; j < 4; ++j) {
            const int b = tb + j;
            double v = alpha * (double)gT(gram, k, a, b);
            if (a == b) v += beta;
            E[a * LDE + b] = (float)v;
        }
    }
    __syncthreads();

    {
        float f[4][4];
#pragma unroll
        for (int i = 0; i < 4; ++i)
#pragma unroll
            for (int j = 0; j < 4; ++j) f[i][j] = 0.0f;
#pragma unroll 4
        for (int t = 0; t < PDIM; ++t) {
            const float4 ea4 = *reinterpret_cast<const float4*>(&E[t * LDE + ta]);
            const float4 eb4 = *reinterpret_cast<const float4*>(&E[t * LDE + tb]);
            const float ea[4] = {ea4.x, ea4.y, ea4.z, ea4.w};
            const float eb[4] = {eb4.x, eb4.y, eb4.z, eb4.w};
#pragma unroll
            for (int i = 0; i < 4; ++i)
#pragma unroll
                for (int j = 0; j < 4; ++j) f[i][j] = fmaf(ea[i], eb[j], f[i][j]);
        }
#pragma unroll
        for (int i = 0; i < 4; ++i)
            *reinterpret_cast<float4*>(&F[(ta + i) * LDE + tb]) =
                make_float4(f[i][0], f[i][1], f[i][2], f[i][3]);
    }
    __syncthreads();

    {
        float h[4][4], g3[4][4];
#pragma unroll
        for (int i = 0; i < 4; ++i)
#pragma unroll
            for (int j = 0; j < 4; ++j) { h[i][j] = 0.0f; g3[i][j] = 0.0f; }
#pragma unroll 4
        for (int t = 0; t < PDIM; ++t) {
            const float4 fa4 = *reinterpret_cast<const float4*>(&F[t * LDE + ta]);
            const float4 fb4 = *reinterpret_cast<const float4*>(&F[t * LDE + tb]);
            const float4 eb4 = *reinterpret_cast<const float4*>(&E[t * LDE + tb]);
            const float fa[4] = {fa4.x, fa4.y, fa4.z, fa4.w};
            const float fb[4] = {fb4.x, fb4.y, fb4.z, fb4.w};
            const float eb[4] = {eb4.x, eb4.y, eb4.z, eb4.w};
#pragma unroll
            for (int i = 0; i < 4; ++i)
#pragma unroll
                for (int j = 0; j < 4; ++j) {
                    h[i][j] = fmaf(fa[i], fb[j], h[i][j]);
                    g3[i][j] = fmaf(fa[i], eb[j], g3[i][j]);
                }
        }
#pragma unroll
        for (int i = 0; i < 4; ++i) {
            *reinterpret_cast<float4*>(&H[(ta + i) * LDE + tb]) =
                make_float4(h[i][0], h[i][1], h[i][2], h[i][3]);
            *reinterpret_cast<float4*>(&G3[(ta + i) * LDE + tb]) =
                make_float4(g3[i][0], g3[i][1], g3[i][2], g3[i][3]);
        }
    }
    __syncthreads();

    double t2 = 0, t3 = 0, t4 = 0, t5 = 0, t6 = 0, t7 = 0, t8 = 0;
#pragma unroll
    for (int i = 0; i < 4; ++i)
#pragma unroll
        for (int j = 0; j < 4; ++j) {
            const int idx = (ta + i) * LDE + tb + j;
            const double e = (double)E[idx];
            const double f = (double)F[idx];
            const double h = (double)H[idx];
            const double g = (double)G3[idx];
            t2 += e * e; t3 += f * e; t4 += f * f;
            t5 += h * e; t6 += h * f; t7 += h * g; t8 += h * h;
        }
#pragma unroll
    for (int off = 32; off > 0; off >>= 1) {
        t2 += __shfl_down(t2, off);
        t3 += __shfl_down(t3, off);
        t4 += __shfl_down(t4, off);
        t5 += __shfl_down(t5, off);
        t6 += __shfl_down(t6, off);
        t7 += __shfl_down(t7, off);
        t8 += __shfl_down(t8, off);
    }
    const int lane = tid & 63;
    const int wid = tid >> 6;
    if (lane == 0) {
        s_red[wid][0] = t2; s_red[wid][1] = t3; s_red[wid][2] = t4;
        s_red[wid][3] = t5; s_red[wid][4] = t6; s_red[wid][5] = t7;
        s_red[wid][6] = t8;
    }
    __syncthreads();
    if (tid == 0) {
        double r[7];
        for (int q = 0; q < 7; ++q) {
            r[q] = 0.0;
            for (int w = 0; w < 4; ++w) r[q] += s_red[w][q];
        }
        const double ld = s_logs
            - r[0] / 2.0 + r[1] / 3.0 - r[2] / 4.0 + r[3] / 5.0
            - r[4] / 6.0 + r[5] / 7.0 - r[6] / 8.0;
        contrib[k] = s_w * ld;
        __threadfence();
        const unsigned old = atomicAdd(ctr, 1u);
        if (old == NCLS) {
            double t = 0.0;
            for (int i = 0; i <= NCLS; ++i)
                t += atomicAdd(&contrib[i], 0.0);
            out[0] = (float)t;
        }
    }
}

extern "C" void kernel_launch(void* const* d_in, const int* in_sizes, int n_in,
                              void* d_out, int out_size, void* d_ws, size_t ws_size,
                              hipStream_t stream) {
    const float* embed = (const float*)d_in[0];
    const int* targets = (const int*)d_in[1];
    float* out = (float*)d_out;
    const int m = in_sizes[0] / PDIM;   // 262144

    char* ws = (char*)d_ws;
    float* gram      = (float*)ws;                  // 163840
    unsigned* ctr    = (unsigned*)(ws + 163840);    // 4
    double* contrib  = (double*)(ws + 163848);      // 88
    int* counts      = (int*)(ws + 163936);         // 40

    hipMemsetAsync(ws, 0, 163844, stream);          // gram + ctr
    hipMemsetAsync(ws + 163936, 0, 40, stream);     // counts

    dim3 g1((m + CHUNK - 1) / CHUNK, NCLS);
    mcr_gram<<<g1, 256, 0, stream>>>(embed, targets, gram, counts, m);
    mcr_logdet<<<NCLS + 1, 256, 0, stream>>>(gram, counts, contrib, ctr, out, m);
}